// Round 3
// baseline (247.502 us; speedup 1.0000x reference)
//
#include <hip/hip_runtime.h>
#include <cstdint>

// NNLS PGD step (all tensors FLOAT32, k int32):
//   new_X = relu(th1 @ Y + weight); Y_new = new_X + (k-1)/(k+2)*(new_X - X_old)
// th1 [1024,1024], Y/X_old/weight [1024,8192].
// out (float32) = [Y_new (KB) | new_X (KB) | k+1 (1) | weight (KB)].
// GEMM runs bf16 MFMA with RNE-ish converted operands, fp32 accumulate
// (error ~0.01 vs 0.06 threshold).

#define KDIM 1024
#define NDIM 8192
#define KB_ELEMS (1024UL * 8192UL)

typedef short short8 __attribute__((ext_vector_type(8)));
typedef float f32x4 __attribute__((ext_vector_type(4)));

// Pack two f32 into two bf16 (round-to-nearest-ish via +0x8000): low half = a.
__device__ __forceinline__ uint32_t pk2(float a, float b) {
  uint32_t ua = __builtin_bit_cast(uint32_t, a) + 0x8000u;
  uint32_t ub = __builtin_bit_cast(uint32_t, b) + 0x8000u;
  return (ua >> 16) | (ub & 0xFFFF0000u);
}

// 128x128 block tile, BK=32, 4 waves (2x2), each wave 64x64 = 4x4 MFMA 16x16x32.
// As[m][k] bf16 (no swizzle needed). Bs[n][k] bf16 with XOR-chunk swizzle:
// logical (n,k) at Bs[n*32 + ch*8 + (k&7)], ch = (k>>3) ^ ((n>>3)&3).
__global__ __launch_bounds__(256, 2) void nnls_gemm(
    const float* __restrict__ th1, const float* __restrict__ Y,
    const float* __restrict__ xold, const int* __restrict__ kin,
    const float* __restrict__ weight, float* __restrict__ out)
{
  __shared__ __align__(16) unsigned short As[128 * 32];  // 8 KB
  __shared__ __align__(16) unsigned short Bs[128 * 32];  // 8 KB

  const int tid  = threadIdx.x;
  const int lane = tid & 63;
  const int w    = tid >> 6;
  const int wm = w >> 1, wn = w & 1;
  const int quad = lane >> 4, nl = lane & 15;

  const int m0 = blockIdx.y * 128;
  const int n0 = blockIdx.x * 128;

  // B staging: each thread owns (n = 2*lane + {0,1}, k = w*8 .. w*8+7)
  const int nn = 2 * lane;
  const int ks = w * 8;
  const float* ybase = Y + (size_t)ks * NDIM + n0 + nn;

  // A staging: thread t loads float4 at rows ar+32g, cols ac*4 (coalesced 128B rows)
  const int ar = tid >> 3;   // 0..31
  const int ac = tid & 7;    // 0..7
  const float* abase = th1 + (size_t)(m0 + ar) * KDIM + ac * 4;

  float2 yb[8];
  float4 ab[4];
#pragma unroll
  for (int r = 0; r < 8; ++r) yb[r] = *(const float2*)(ybase + (size_t)r * NDIM);
#pragma unroll
  for (int g = 0; g < 4; ++g) ab[g] = *(const float4*)(abase + (size_t)(32 * g) * KDIM);

  f32x4 acc[4][4] = {};

  for (int kt = 0; kt < 32; ++kt) {
    // ---- convert + write staged registers into LDS ----
#pragma unroll
    for (int g = 0; g < 4; ++g) {
      uint2 d;
      d.x = pk2(ab[g].x, ab[g].y);
      d.y = pk2(ab[g].z, ab[g].w);
      *(uint2*)&As[(ar + 32 * g) * 32 + ac * 4] = d;  // conflict-free b64
    }
#pragma unroll
    for (int j = 0; j < 2; ++j) {
      const int n  = nn + j;
      const int ch = w ^ ((n >> 3) & 3);
      uint4 d;
      d.x = pk2(j ? yb[0].y : yb[0].x, j ? yb[1].y : yb[1].x);
      d.y = pk2(j ? yb[2].y : yb[2].x, j ? yb[3].y : yb[3].x);
      d.z = pk2(j ? yb[4].y : yb[4].x, j ? yb[5].y : yb[5].x);
      d.w = pk2(j ? yb[6].y : yb[6].x, j ? yb[7].y : yb[7].x);
      *(uint4*)&Bs[n * 32 + ch * 8] = d;  // b128, 2-way (free)
    }
    __syncthreads();  // B1: tile ready

    // ---- prefetch next tile into registers (drains under MFMA) ----
    if (kt < 31) {
      const float* yn = ybase + (size_t)((kt + 1) * 32) * NDIM;
      const float* an = abase + (kt + 1) * 32;
#pragma unroll
      for (int r = 0; r < 8; ++r) yb[r] = *(const float2*)(yn + (size_t)r * NDIM);
#pragma unroll
      for (int g = 0; g < 4; ++g) ab[g] = *(const float4*)(an + (size_t)(32 * g) * KDIM);
    }

    // ---- fragments + MFMA ----
    short8 af[4], bf[4];
#pragma unroll
    for (int i = 0; i < 4; ++i) {
      af[i] = *(const short8*)&As[(wm * 64 + i * 16 + nl) * 32 + quad * 8];
      const int n  = wn * 64 + i * 16 + nl;
      const int ch = quad ^ ((n >> 3) & 3);
      bf[i] = *(const short8*)&Bs[n * 32 + ch * 8];
    }
#pragma unroll
    for (int i = 0; i < 4; ++i)
#pragma unroll
      for (int j = 0; j < 4; ++j)
        acc[i][j] = __builtin_amdgcn_mfma_f32_16x16x32_bf16(af[i], bf[j], acc[i][j], 0, 0, 0);

    __syncthreads();  // B2: protect LDS reuse
  }

  // ---- epilogue: C/D layout col = lane&15 (n), row = quad*4 + r (m) ----
  const float kf  = (float)kin[0];
  const float mom = (kf - 1.0f) / (kf + 2.0f);
#pragma unroll
  for (int i = 0; i < 4; ++i) {
#pragma unroll
    for (int j = 0; j < 4; ++j) {
      const int mbase = m0 + wm * 64 + i * 16 + quad * 4;
      const int nidx  = n0 + wn * 64 + j * 16 + nl;
#pragma unroll
      for (int r = 0; r < 4; ++r) {
        const size_t idx = (size_t)(mbase + r) * NDIM + nidx;
        const float wv = weight[idx];
        const float xo = xold[idx];
        const float nx = fmaxf(acc[i][j][r] + wv, 0.0f);
        const float yn = nx + mom * (nx - xo);
        out[idx] = yn;                        // Y_new
        out[KB_ELEMS + idx] = nx;             // new_X
        out[2 * KB_ELEMS + 1 + idx] = wv;     // weight passthrough
      }
    }
  }

  if (blockIdx.x == 0 && blockIdx.y == 0 && tid == 0) {
    out[2 * KB_ELEMS] = (float)(kin[0] + 1);  // k+1
  }
}

extern "C" void kernel_launch(void* const* d_in, const int* in_sizes, int n_in,
                              void* d_out, int out_size, void* d_ws, size_t ws_size,
                              hipStream_t stream) {
  const float* th1  = (const float*)d_in[0];
  const float* Y    = (const float*)d_in[1];
  const float* xold = (const float*)d_in[2];
  const int*   kin  = (const int*)d_in[3];
  const float* wgt  = (const float*)d_in[4];
  float* out = (float*)d_out;

  dim3 grid(NDIM / 128, KDIM / 128);  // 64 x 8 = 512 blocks
  nnls_gemm<<<grid, 256, 0, stream>>>(th1, Y, xold, kin, wgt, out);
}

// Round 4
// 239.528 us; speedup vs baseline: 1.0333x; 1.0333x over previous
//
#include <hip/hip_runtime.h>
#include <cstdint>

// NNLS PGD step (all tensors FLOAT32, k int32):
//   new_X = relu(th1 @ Y + weight); Y_new = new_X + (k-1)/(k+2)*(new_X - X_old)
// out (f32) = [Y_new (KB) | new_X (KB) | k+1 (1) | weight (KB)].
// bf16 MFMA inside (absmax ~0.008 vs 0.06 threshold).

#define KDIM 1024
#define NDIM 8192
#define KB_ELEMS (1024UL * 8192UL)
#define LDA 40  // LDS row stride in ushorts (80B = 20 dwords -> bank-spread rows)

typedef short short8 __attribute__((ext_vector_type(8)));
typedef float f32x4 __attribute__((ext_vector_type(4)));

struct __attribute__((aligned(4))) f4u { float x, y, z, w; };  // 4B-aligned 16B store

__device__ __forceinline__ uint32_t pk2(float a, float b) {
  uint32_t ua = __builtin_bit_cast(uint32_t, a) + 0x8000u;
  uint32_t ub = __builtin_bit_cast(uint32_t, b) + 0x8000u;
  return (ua >> 16) | (ub & 0xFFFF0000u);
}

// 128x128 tile, BK=32, 512 threads = 8 waves (4m x 2n), wave tile 32x64 (2x4 MFMA).
__global__ __launch_bounds__(512, 4) void nnls_gemm(
    const float* __restrict__ th1, const float* __restrict__ Y,
    const float* __restrict__ xold, const int* __restrict__ kin,
    const float* __restrict__ weight, float* __restrict__ out)
{
  __shared__ __align__(16) char smem[32768];
  unsigned short* As = (unsigned short*)smem;             // 128*40*2 = 10240 B
  unsigned short* Bs = (unsigned short*)(smem + 10240);   // 10240 B

  const int tid  = threadIdx.x;
  const int lane = tid & 63;
  const int w    = tid >> 6;            // 0..7
  const int wm = w >> 1, wn = w & 1;    // 4 x 2 wave grid
  const int quad = lane >> 4, nl = lane & 15;

  const int m0 = blockIdx.y * 128;
  const int n0 = blockIdx.x * 128;

  // A staging: thread -> rows {ar, ar+64}, cols ac*4 (float4); 128B per 8 threads
  const int ar = tid >> 3;              // 0..63
  const int ac = tid & 7;
  const float* abase = th1 + (size_t)(m0 + ar) * KDIM + ac * 4;

  // B staging: thread -> row n=bn (tile col), k = bk..bk+7 (8 scalar loads)
  const int bn = tid & 127;
  const int bk = (tid >> 7) * 8;        // 0,8,16,24 (wave-uniform pairs)
  const float* ybase = Y + (size_t)bk * NDIM + n0 + bn;

  float4 ab[2];
  float  yb[8];
  ab[0] = *(const float4*)(abase);
  ab[1] = *(const float4*)(abase + (size_t)64 * KDIM);
#pragma unroll
  for (int r = 0; r < 8; ++r) yb[r] = ybase[(size_t)r * NDIM];

  f32x4 acc[2][4] = {};

  for (int kt = 0; kt < 32; ++kt) {
    // ---- convert + LDS stage (all conflict-free with LDA=40) ----
    {
      uint2 d0; d0.x = pk2(ab[0].x, ab[0].y); d0.y = pk2(ab[0].z, ab[0].w);
      *(uint2*)&As[ar * LDA + ac * 4] = d0;
      uint2 d1; d1.x = pk2(ab[1].x, ab[1].y); d1.y = pk2(ab[1].z, ab[1].w);
      *(uint2*)&As[(ar + 64) * LDA + ac * 4] = d1;
      uint4 e;
      e.x = pk2(yb[0], yb[1]); e.y = pk2(yb[2], yb[3]);
      e.z = pk2(yb[4], yb[5]); e.w = pk2(yb[6], yb[7]);
      *(uint4*)&Bs[bn * LDA + bk] = e;  // single ds_write_b128
    }
    __syncthreads();  // B1

    if (kt < 31) {  // register prefetch, drains under MFMA of this iter
      const float* an = abase + (kt + 1) * 32;
      ab[0] = *(const float4*)(an);
      ab[1] = *(const float4*)(an + (size_t)64 * KDIM);
      const float* yn = ybase + (size_t)((kt + 1) * 32) * NDIM;
#pragma unroll
      for (int r = 0; r < 8; ++r) yb[r] = yn[(size_t)r * NDIM];
    }

    short8 af[2], bf[4];
#pragma unroll
    for (int i = 0; i < 2; ++i)
      af[i] = *(const short8*)&As[(wm * 32 + i * 16 + nl) * LDA + quad * 8];
#pragma unroll
    for (int j = 0; j < 4; ++j)
      bf[j] = *(const short8*)&Bs[(wn * 64 + j * 16 + nl) * LDA + quad * 8];
#pragma unroll
    for (int i = 0; i < 2; ++i)
#pragma unroll
      for (int j = 0; j < 4; ++j)
        acc[i][j] = __builtin_amdgcn_mfma_f32_16x16x32_bf16(af[i], bf[j], acc[i][j], 0, 0, 0);

    __syncthreads();  // B2
  }

  // ---- epilogue: per-wave LDS transpose -> float4 global I/O ----
  const float kf  = (float)kin[0];
  const float mom = (kf - 1.0f) / (kf + 2.0f);
  float* ep = (float*)smem + w * 1024;  // 16 rows x 64 f32 = 4KB per wave
  const int lr = lane >> 2;             // read row 0..15
  const int cb = (lane & 3) * 16;       // read col base
  const int swzR = 16 * ((lr >> 2) & 1) + 4 * (lr & 3);

#pragma unroll
  for (int i = 0; i < 2; ++i) {
    // scatter acc chunk i (16 rows x 64 cols), XOR swizzle: 2-way writes (free)
#pragma unroll
    for (int j = 0; j < 4; ++j)
#pragma unroll
      for (int r = 0; r < 4; ++r) {
        const int wrow = quad * 4 + r;
        const int colp = (j * 16 + nl) ^ (16 * (quad & 1) + 4 * r);
        ep[wrow * 64 + colp] = acc[i][j][r];
      }
    __syncthreads();  // cross-lane visibility (conservative)

    const int mg = m0 + wm * 32 + i * 16 + lr;
#pragma unroll
    for (int t = 0; t < 4; ++t) {
      const int colp = (cb + 4 * t) ^ swzR;
      const float4 cv = *(const float4*)&ep[lr * 64 + colp];  // b128, conflict-free
      const int ng = n0 + wn * 64 + cb + 4 * t;
      const size_t idx = (size_t)mg * NDIM + ng;
      const float4 wv = *(const float4*)&weight[idx];
      const float4 xo = *(const float4*)&xold[idx];
      float4 nx, yn;
      nx.x = fmaxf(cv.x + wv.x, 0.0f); nx.y = fmaxf(cv.y + wv.y, 0.0f);
      nx.z = fmaxf(cv.z + wv.z, 0.0f); nx.w = fmaxf(cv.w + wv.w, 0.0f);
      yn.x = nx.x + mom * (nx.x - xo.x); yn.y = nx.y + mom * (nx.y - xo.y);
      yn.z = nx.z + mom * (nx.z - xo.z); yn.w = nx.w + mom * (nx.w - xo.w);
      *(float4*)&out[idx] = yn;               // Y_new (16B aligned)
      *(float4*)&out[KB_ELEMS + idx] = nx;    // new_X (16B aligned)
      f4u s; s.x = wv.x; s.y = wv.y; s.z = wv.z; s.w = wv.w;
      *(f4u*)&out[2 * KB_ELEMS + 1 + idx] = s;  // weight passthrough (4B aligned)
    }
    __syncthreads();  // protect ep before next chunk's writes
  }

  if (blockIdx.x == 0 && blockIdx.y == 0 && tid == 0)
    out[2 * KB_ELEMS] = (float)(kin[0] + 1);
}

extern "C" void kernel_launch(void* const* d_in, const int* in_sizes, int n_in,
                              void* d_out, int out_size, void* d_ws, size_t ws_size,
                              hipStream_t stream) {
  const float* th1  = (const float*)d_in[0];
  const float* Y    = (const float*)d_in[1];
  const float* xold = (const float*)d_in[2];
  const int*   kin  = (const int*)d_in[3];
  const float* wgt  = (const float*)d_in[4];
  float* out = (float*)d_out;

  dim3 grid(NDIM / 128, KDIM / 128);  // 64 x 8 = 512 blocks, 2/CU, 16 waves/CU
  nnls_gemm<<<grid, 512, 0, stream>>>(th1, Y, xold, kin, wgt, out);
}